// Round 15
// baseline (119.188 us; speedup 1.0000x reference)
//
#include <hip/hip_runtime.h>
#include <hip/hip_bf16.h>
#include <math.h>

#define NH 12
#define DH 64
#define BB 2
#define NN 2048
#define DM 768

typedef short v8s __attribute__((ext_vector_type(8)));
typedef float v4f __attribute__((ext_vector_type(4)));
typedef float v16f __attribute__((ext_vector_type(16)));

__device__ __forceinline__ unsigned short f2bf(float f) {
    union { float f; unsigned u; } x; x.f = f;
    unsigned r = x.u + 0x7fffu + ((x.u >> 16) & 1u);
    return (unsigned short)(r >> 16);
}

__device__ __forceinline__ int cvtpk(float lo, float hi2) {
    int r;
    asm("v_cvt_pk_bf16_f32 %0, %1, %2" : "=v"(r) : "v"(lo), "v"(hi2));
    return r;
}

__device__ __forceinline__ void glds16(const void* g, void* l) {
    __builtin_amdgcn_global_load_lds((const __attribute__((address_space(1))) void*)g,
                                     (__attribute__((address_space(3))) void*)l, 16, 0, 0);
}

// ---- fused casts: blocks [0,3072) cast x fp32->bf16; blocks [3072,3648) transpose weights ----
__global__ __launch_bounds__(256) void cast_fused_k(
    const float* __restrict__ x, unsigned short* __restrict__ xb,
    const float* __restrict__ w0, const float* __restrict__ w1,
    const float* __restrict__ w2, const float* __restrict__ w3,
    unsigned short* __restrict__ o0, unsigned short* __restrict__ o1,
    unsigned short* __restrict__ o2, unsigned short* __restrict__ o3) {
    __shared__ unsigned short t[64][65];
    int bid = blockIdx.x;
    if (bid < 3072) {
        int i = (bid * 256 + threadIdx.x) * 4;
        float4 v = *(const float4*)(x + i);
        ushort4 o;
        o.x = f2bf(v.x); o.y = f2bf(v.y); o.z = f2bf(v.z); o.w = f2bf(v.w);
        *(ushort4*)(xb + i) = o;
        return;
    }
    int idx = bid - 3072;
    int m = idx / 144, xt = idx % 144;
    const float* in; unsigned short* out;
    switch (m) {
        case 0: in = w0; out = o0; break;
        case 1: in = w1; out = o1; break;
        case 2: in = w2; out = o2; break;
        default: in = w3; out = o3; break;
    }
    int kt = xt / 12, ct = xt % 12;
    int rr = threadIdx.x >> 4, cc = threadIdx.x & 15;
#pragma unroll
    for (int it = 0; it < 4; it++) {
        int row = kt * 64 + it * 16 + rr;
        int col = ct * 64 + cc * 4;
        float4 v = *(const float4*)(in + row * 768 + col);
        t[it * 16 + rr][cc * 4 + 0] = f2bf(v.x);
        t[it * 16 + rr][cc * 4 + 1] = f2bf(v.y);
        t[it * 16 + rr][cc * 4 + 2] = f2bf(v.z);
        t[it * 16 + rr][cc * 4 + 3] = f2bf(v.w);
    }
    __syncthreads();
#pragma unroll
    for (int it = 0; it < 4; it++) {
        int c_l = it * 16 + rr;
        int k_l = cc * 4;
        ushort4 o;
        o.x = t[k_l + 0][c_l];
        o.y = t[k_l + 1][c_l];
        o.z = t[k_l + 2][c_l];
        o.w = t[k_l + 3][c_l];
        *(ushort4*)(out + (ct * 64 + c_l) * 768 + kt * 64 + k_l) = o;
    }
}

// ---- fused QKV projection as one GEMM over N=2304; 8 waves; XCD-swizzled 1-D grid ----
__global__ __launch_bounds__(512) void qkv_gemm_k(
    const unsigned short* __restrict__ xb,
    const unsigned short* __restrict__ wqT, const unsigned short* __restrict__ wkT,
    const unsigned short* __restrict__ wvT,
    const float* __restrict__ bq, const float* __restrict__ bk, const float* __restrict__ bv,
    unsigned short* __restrict__ q, unsigned short* __restrict__ k, unsigned short* __restrict__ vT) {
    __shared__ unsigned short Abuf[3][128 * 32];
    __shared__ unsigned short Bbuf[3][128 * 32];

    int lin = blockIdx.x;
    int swz = (lin & 7) * 72 + (lin >> 3);
    int ctile = swz % 18;
    int mtile = swz / 18;
    int mat = ctile / 6;
    int col0 = (ctile % 6) * 128;
    const unsigned short* Bsrc = (mat == 0) ? wqT : ((mat == 1) ? wkT : wvT);
    const float* bias = (mat == 0) ? bq : ((mat == 1) ? bk : bv);

    int tid = threadIdx.x;
    int w = tid >> 6, l = tid & 63;
    int q16 = l & 15, g = l >> 4;
    int wr = w >> 2, wc = w & 3;

    int srow = tid >> 2;
    int ss = tid & 3;
    int c16s = ss ^ ((srow >> 1) & 3);

    auto stage = [&](int tt, int buf) {
        int k0 = tt * 32;
        glds16(xb + (mtile * 128 + srow) * 768 + k0 + (c16s << 3),
               (char*)&Abuf[buf][0] + tid * 16);
        glds16(Bsrc + (col0 + srow) * 768 + k0 + (c16s << 3),
               (char*)&Bbuf[buf][0] + tid * 16);
    };

    v4f zero = {0.f, 0.f, 0.f, 0.f};
    v4f acc[4][2];
#pragma unroll
    for (int i = 0; i < 4; i++)
#pragma unroll
        for (int j = 0; j < 2; j++) acc[i][j] = zero;

    stage(0, 0);
    stage(1, 1);
    asm volatile("s_waitcnt vmcnt(2)" ::: "memory");
    __builtin_amdgcn_s_barrier();
    asm volatile("" ::: "memory");

    int rd = 0;
    for (int tt = 0; tt < 24; ++tt) {
        int st = rd + 2; if (st >= 3) st -= 3;
        if (tt + 2 < 24) stage(tt + 2, st);
        const char* Ab = (const char*)&Abuf[rd][0];
        const char* Bb = (const char*)&Bbuf[rd][0];
        v8s af[4], bf[2];
#pragma unroll
        for (int f = 0; f < 4; f++) {
            int arow = wr * 64 + f * 16 + q16;
            af[f] = *(const v8s*)(Ab + arow * 64 + ((g ^ ((arow >> 1) & 3)) << 4));
        }
#pragma unroll
        for (int j = 0; j < 2; j++) {
            int brow = wc * 32 + j * 16 + q16;
            bf[j] = *(const v8s*)(Bb + brow * 64 + ((g ^ ((brow >> 1) & 3)) << 4));
        }
        __builtin_amdgcn_s_setprio(1);
#pragma unroll
        for (int i = 0; i < 4; i++)
#pragma unroll
            for (int j = 0; j < 2; j++)
                acc[i][j] = __builtin_amdgcn_mfma_f32_16x16x32_bf16(af[i], bf[j], acc[i][j], 0, 0, 0);
        __builtin_amdgcn_s_setprio(0);
        asm volatile("s_waitcnt vmcnt(2)" ::: "memory");
        __builtin_amdgcn_s_barrier();
        asm volatile("" ::: "memory");
        rd = (rd + 1 == 3) ? 0 : rd + 1;
    }

    const float QSCL = 0.125f * 1.44269504088896340736f;
#pragma unroll
    for (int i = 0; i < 4; i++)
#pragma unroll
        for (int j = 0; j < 2; j++)
#pragma unroll
            for (int r = 0; r < 4; r++) {
                int gr = mtile * 128 + wr * 64 + i * 16 + 4 * g + r;
                int gcl = col0 + wc * 32 + j * 16 + q16;
                int b = gr / NN, n = gr % NN;
                int h = gcl / DH, d = gcl % DH;
                int bh = b * NH + h;
                float v = acc[i][j][r] + bias[gcl];
                if (mat == 0)      q[(bh * NN + n) * DH + d]  = f2bf(v * QSCL);
                else if (mat == 1) k[(bh * NN + n) * DH + d]  = f2bf(v);
                else               vT[(bh * DH + d) * NN + n] = f2bf(v);
            }
}

// ---- flash attention: 32x32 MFMA; 8 waves = 2 q-strips(32q) x 4 kv-quarters(512); KVBLK=32 ----
// In-register P redistribution (MKFRAG, R5-verified); K/V quarters in paired 128B-row LDS
// (R12-verified layouts); 4-way online-softmax merge through dead K/V LDS at the end.
#define MKFRAG(PC, BASE, FR) {                                                     \
    int a0 = cvtpk(PC[BASE + 0], PC[BASE + 1]), a1 = cvtpk(PC[BASE + 2], PC[BASE + 3]); \
    int b0 = cvtpk(PC[BASE + 4], PC[BASE + 5]), b1 = cvtpk(PC[BASE + 6], PC[BASE + 7]); \
    int t0 = hi ? a0 : b0, t1 = hi ? a1 : b1;                                      \
    int r0 = __shfl_xor(t0, 32), r1 = __shfl_xor(t1, 32);                          \
    union { int i[4]; v8s s; } u_;                                                 \
    u_.i[0] = hi ? r0 : a0; u_.i[1] = hi ? r1 : a1;                                \
    u_.i[2] = hi ? b0 : r0; u_.i[3] = hi ? b1 : r1;                                \
    FR = u_.s; }

__global__ __launch_bounds__(512) void attn_k(
    const unsigned short* __restrict__ q, const unsigned short* __restrict__ k,
    const unsigned short* __restrict__ vT, unsigned short* __restrict__ z) {
    // [0,32768): K quarters [4][2][4096]; [32768,65536): V quarters [4][2][4096].
    // After the loop: po (3x64x64 f32 = 48KB) at 0; pml (2x4x64 f32 = 2KB) at 49152.
    __shared__ __align__(16) char smem[65536];

    int bh = blockIdx.x % 24;
    int qt = blockIdx.x / 24;                  // 0..31, 64 q-rows per block
    int b = bh / NH, h = bh % NH;
    int tid = threadIdx.x;
    int w = tid >> 6, l = tid & 63;
    int ln = l & 31, hi = l >> 5;
    int qd = w & 3, strip = w >> 2;            // kv-quarter, q-strip

    const unsigned short* qp = q + (size_t)bh * NN * DH;
    const unsigned short* kp = k + (size_t)bh * NN * DH;
    const unsigned short* vp = vT + (size_t)bh * DH * NN;

    int qrow = qt * 64 + strip * 32 + ln;
    v8s qf[4];
#pragma unroll
    for (int ks = 0; ks < 4; ++ks)
        qf[ks] = *(const v8s*)(qp + qrow * DH + 16 * ks + 8 * hi);

    // staging: thread tid serves quarter (tid>>7); 128 threads cover 256 slots of K and of V
    int sq = tid >> 7;
    int s7 = tid & 127;
    auto stage = [&](int t, int buf) {
        int kv0 = sq * (NN / 4) + t * 32;
#pragma unroll
        for (int i = 0; i < 2; ++i) {
            int slot = s7 + 128 * i;           // 0..255
            int row = slot >> 3, psl = slot & 7;
            int j = psl ^ (row & 7);           // logical slot stored at phys psl
            glds16(kp + (kv0 + row) * DH + (j << 3),
                   smem + sq * 8192 + buf * 4096 + slot * 16);
            int vd = row + ((j >> 2) << 5);    // V row r holds d=r (j<4) and d=r+32 (j>=4)
            glds16(vp + (size_t)vd * NN + kv0 + ((j & 3) << 3),
                   smem + 32768 + sq * 8192 + buf * 4096 + slot * 16);
        }
    };

    v16f o0, o1;
#pragma unroll
    for (int i = 0; i < 16; i++) { o0[i] = 0.f; o1[i] = 0.f; }
    float mrow = -INFINITY, lsum = 0.f;

    stage(0, 0);
    __syncthreads();

    for (int t = 0; t < 16; ++t) {
        int cur = t & 1;
        if (t + 1 < 16) stage(t + 1, cur ^ 1);
        const char* kb = smem + qd * 8192 + cur * 4096;
        const char* vb = smem + 32768 + qd * 8192 + cur * 4096;

        // ---- QK^T: S^T[32 kv][32 q] ----
        v16f s;
#pragma unroll
        for (int i = 0; i < 16; i++) s[i] = 0.f;
        {
            v8s kf[4];
#pragma unroll
            for (int ks = 0; ks < 4; ++ks)
                kf[ks] = *(const v8s*)(kb + ln * 128 + (((2 * ks + hi) ^ (ln & 7)) << 4));
            __builtin_amdgcn_s_setprio(1);
#pragma unroll
            for (int ks = 0; ks < 4; ++ks)
                s = __builtin_amdgcn_mfma_f32_32x32x16_bf16(kf[ks], qf[ks], s, 0, 0, 0);
            __builtin_amdgcn_s_setprio(0);
        }

        // ---- online softmax (4-chain max, defer-max THR=8) ----
        float x0 = -1e30f, x1 = -1e30f, x2 = -1e30f, x3 = -1e30f;
#pragma unroll
        for (int i = 0; i < 16; i += 4) {
            x0 = fmaxf(x0, s[i]);     x1 = fmaxf(x1, s[i + 1]);
            x2 = fmaxf(x2, s[i + 2]); x3 = fmaxf(x3, s[i + 3]);
        }
        float vmax = fmaxf(fmaxf(x0, x1), fmaxf(x2, x3));
        vmax = fmaxf(vmax, __shfl_xor(vmax, 32));

        if (!__all(vmax <= mrow + 8.f)) {
            float mn = fmaxf(mrow, vmax);
            float sc = exp2f(mrow - mn);
#pragma unroll
            for (int r = 0; r < 16; ++r) {
                int addr = 4 * ((r & 3) + 8 * (r >> 2)) + (hi << 4);
                float scr = __uint_as_float(
                    __builtin_amdgcn_ds_bpermute(addr, __float_as_uint(sc)));
                o0[r] *= scr; o1[r] *= scr;
            }
            lsum *= sc;
            mrow = mn;
        }

        float r0 = 0.f, r1 = 0.f, r2 = 0.f, r3 = 0.f;
#pragma unroll
        for (int i = 0; i < 16; i += 4) {
            s[i] = exp2f(s[i] - mrow);         s[i + 1] = exp2f(s[i + 1] - mrow);
            s[i + 2] = exp2f(s[i + 2] - mrow); s[i + 3] = exp2f(s[i + 3] - mrow);
            r0 += s[i]; r1 += s[i + 1]; r2 += s[i + 2]; r3 += s[i + 3];
        }
        float rs = (r0 + r1) + (r2 + r3);
        rs += __shfl_xor(rs, 32);
        lsum += rs;

        // ---- P fragments in-register ----
        v8s pf[2];
        MKFRAG(s, 0, pf[0]);
        MKFRAG(s, 8, pf[1]);

        // ---- PV: O[32 q][64 d] ----
        {
            v8s vf0[2], vf1[2];
#pragma unroll
            for (int ks = 0; ks < 2; ++ks) {
                vf0[ks] = *(const v8s*)(vb + ln * 128 + (((2 * ks + hi) ^ (ln & 7)) << 4));
                vf1[ks] = *(const v8s*)(vb + ln * 128 + (((4 + 2 * ks + hi) ^ (ln & 7)) << 4));
            }
            __builtin_amdgcn_s_setprio(1);
#pragma unroll
            for (int ks = 0; ks < 2; ++ks) {
                o0 = __builtin_amdgcn_mfma_f32_32x32x16_bf16(pf[ks], vf0[ks], o0, 0, 0, 0);
                o1 = __builtin_amdgcn_mfma_f32_32x32x16_bf16(pf[ks], vf1[ks], o1, 0, 0, 0);
            }
            __builtin_amdgcn_s_setprio(0);
        }
        __syncthreads();
    }

    // ---- 4-way merge through dead K/V LDS ----
    float* po = (float*)smem;                  // [3][64 q][64 d]
    float* pml = (float*)(smem + 49152);       // [2][4][64]
    int qg = strip * 32 + ln;

    if (qd != 0) {
#pragma unroll
        for (int r = 0; r < 16; ++r) {
            int qr = (r & 3) + 8 * (r >> 2) + 4 * hi;
            int row = strip * 32 + qr;
            po[((qd - 1) * 64 + row) * 64 + ln]      = o0[r];
            po[((qd - 1) * 64 + row) * 64 + 32 + ln] = o1[r];
        }
        pml[(0 * 4 + qd) * 64 + qg] = mrow;
        pml[(1 * 4 + qd) * 64 + qg] = lsum;
    }
    __syncthreads();
    if (qd == 0) {
        float m1 = pml[(0 * 4 + 1) * 64 + qg], l1 = pml[(1 * 4 + 1) * 64 + qg];
        float m2 = pml[(0 * 4 + 2) * 64 + qg], l2 = pml[(1 * 4 + 2) * 64 + qg];
        float m3 = pml[(0 * 4 + 3) * 64 + qg], l3 = pml[(1 * 4 + 3) * 64 + qg];
        float M = fmaxf(fmaxf(mrow, m1), fmaxf(m2, m3));
        float w0 = exp2f(mrow - M), w1_ = exp2f(m1 - M);
        float w2_ = exp2f(m2 - M), w3_ = exp2f(m3 - M);
        float inv = 1.f / (lsum * w0 + l1 * w1_ + l2 * w2_ + l3 * w3_);
        w0 *= inv; w1_ *= inv; w2_ *= inv; w3_ *= inv;
#pragma unroll
        for (int r = 0; r < 16; ++r) {
            int qr = (r & 3) + 8 * (r >> 2) + 4 * hi;
            int addr = qr * 4;
            float W0 = __uint_as_float(__builtin_amdgcn_ds_bpermute(addr, __float_as_uint(w0)));
            float W1 = __uint_as_float(__builtin_amdgcn_ds_bpermute(addr, __float_as_uint(w1_)));
            float W2 = __uint_as_float(__builtin_amdgcn_ds_bpermute(addr, __float_as_uint(w2_)));
            float W3 = __uint_as_float(__builtin_amdgcn_ds_bpermute(addr, __float_as_uint(w3_)));
            int row = strip * 32 + qr;
            float z0 = o0[r] * W0 + po[(0 * 64 + row) * 64 + ln] * W1
                     + po[(1 * 64 + row) * 64 + ln] * W2 + po[(2 * 64 + row) * 64 + ln] * W3;
            float z1 = o1[r] * W0 + po[(0 * 64 + row) * 64 + 32 + ln] * W1
                     + po[(1 * 64 + row) * 64 + 32 + ln] * W2 + po[(2 * 64 + row) * 64 + 32 + ln] * W3;
            int n = qt * 64 + row;
            z[((size_t)(b * NN + n)) * DM + h * DH + ln]      = f2bf(z0);
            z[((size_t)(b * NN + n)) * DM + h * DH + 32 + ln] = f2bf(z1);
        }
    }
}

// ---- output projection: z[4096,768] @ wo + bo -> fp32; 8 waves; XCD-swizzled 1-D grid ----
__global__ __launch_bounds__(512) void out_gemm_k(
    const unsigned short* __restrict__ zb, const unsigned short* __restrict__ woT,
    const float* __restrict__ bo, float* __restrict__ out) {
    __shared__ unsigned short Abuf[3][128 * 32];
    __shared__ unsigned short Bbuf[3][128 * 32];

    int lin = blockIdx.x;
    int swz = (lin & 7) * 24 + (lin >> 3);
    int ctile = swz % 6;
    int mtile = swz / 6;
    int col0 = ctile * 128;

    int tid = threadIdx.x;
    int w = tid >> 6, l = tid & 63;
    int q16 = l & 15, g = l >> 4;
    int wr = w >> 2, wc = w & 3;

    int srow = tid >> 2;
    int ss = tid & 3;
    int c16s = ss ^ ((srow >> 1) & 3);

    auto stage = [&](int tt, int buf) {
        int k0 = tt * 32;
        glds16(zb + (mtile * 128 + srow) * 768 + k0 + (c16s << 3),
               (char*)&Abuf[buf][0] + tid * 16);
        glds16(woT + (col0 + srow) * 768 + k0 + (c16s << 3),
               (char*)&Bbuf[buf][0] + tid * 16);
    };

    v4f zero = {0.f, 0.f, 0.f, 0.f};
    v4f acc[4][2];
#pragma unroll
    for (int i = 0; i < 4; i++)
#pragma unroll
        for (int j = 0; j < 2; j++) acc[i][j] = zero;

    stage(0, 0);
    stage(1, 1);
    asm volatile("s_waitcnt vmcnt(2)" ::: "memory");
    __builtin_amdgcn_s_barrier();
    asm volatile("" ::: "memory");

    int rd = 0;
    for (int tt = 0; tt < 24; ++tt) {
        int st = rd + 2; if (st >= 3) st -= 3;
        if (tt + 2 < 24) stage(tt + 2, st);
        const char* Ab = (const char*)&Abuf[rd][0];
        const char* Bb = (const char*)&Bbuf[rd][0];
        v8s af[4], bf[2];
#pragma unroll
        for (int f = 0; f < 4; f++) {
            int arow = wr * 64 + f * 16 + q16;
            af[f] = *(const v8s*)(Ab + arow * 64 + ((g ^ ((arow >> 1) & 3)) << 4));
        }
#pragma unroll
        for (int j = 0; j < 2; j++) {
            int brow = wc * 32 + j * 16 + q16;
            bf[j] = *(const v8s*)(Bb + brow * 64 + ((g ^ ((brow >> 1) & 3)) << 4));
        }
        __builtin_amdgcn_s_setprio(1);
#pragma unroll
        for (int i = 0; i < 4; i++)
#pragma unroll
            for (int j = 0; j < 2; j++)
                acc[i][j] = __builtin_amdgcn_mfma_f32_16x16x32_bf16(af[i], bf[j], acc[i][j], 0, 0, 0);
        __builtin_amdgcn_s_setprio(0);
        asm volatile("s_waitcnt vmcnt(2)" ::: "memory");
        __builtin_amdgcn_s_barrier();
        asm volatile("" ::: "memory");
        rd = (rd + 1 == 3) ? 0 : rd + 1;
    }

#pragma unroll
    for (int i = 0; i < 4; i++)
#pragma unroll
        for (int j = 0; j < 2; j++)
#pragma unroll
            for (int r = 0; r < 4; r++) {
                int gr = mtile * 128 + wr * 64 + i * 16 + 4 * g + r;
                int gc = col0 + wc * 32 + j * 16 + q16;
                out[gr * 768 + gc] = acc[i][j][r] + bo[gc];
            }
}

extern "C" void kernel_launch(void* const* d_in, const int* in_sizes, int n_in,
                              void* d_out, int out_size, void* d_ws, size_t ws_size,
                              hipStream_t stream) {
    const float* x  = (const float*)d_in[0];
    const float* wq = (const float*)d_in[1];
    const float* bq = (const float*)d_in[2];
    const float* wk = (const float*)d_in[3];
    const float* bk = (const float*)d_in[4];
    const float* wv = (const float*)d_in[5];
    const float* bv = (const float*)d_in[6];
    const float* wo = (const float*)d_in[7];
    const float* bo = (const float*)d_in[8];
    float* out = (float*)d_out;

    const int NX = BB * NN * DM;
    const int NW = 768 * 768;

    unsigned short* wsp = (unsigned short*)d_ws;
    unsigned short* xb  = wsp;
    unsigned short* wqT = xb + NX;
    unsigned short* wkT = wqT + NW;
    unsigned short* wvT = wkT + NW;
    unsigned short* woT = wvT + NW;
    unsigned short* qb  = woT + NW;
    unsigned short* kb  = qb + NX;
    unsigned short* vTb = kb + NX;
    unsigned short* zb  = vTb + NX;

    cast_fused_k<<<3648, 256, 0, stream>>>(x, xb, wq, wk, wv, wo, wqT, wkT, wvT, woT);
    qkv_gemm_k<<<576, 512, 0, stream>>>(xb, wqT, wkT, wvT, bq, bk, bv, qb, kb, vTb);
    attn_k<<<BB * NH * (NN / 64), 512, 0, stream>>>(qb, kb, vTb, zb);
    out_gemm_k<<<192, 512, 0, stream>>>(zb, woT, bo, out);
}